// Round 17
// baseline (171.095 us; speedup 1.0000x reference)
//
#include <hip/hip_runtime.h>
#include <hip/hip_bf16.h>

// Problem constants
#define IN_DIM 128
#define HID    64
#define NFW    8256     // IN*HID + HID
#define BATCH  256
#define K2     16512    // 2*NFW
#define BM     64       // rows per m-block
#define NMB    129      // 8256/64
#define KSPLIT 6
#define NT_PER 43       // k-tiles (of 64) per split; 6*43 = 258
#define GRID_M 774      // NMB * KSPLIT

typedef float f32x4 __attribute__((ext_vector_type(4)));
typedef short bf16x8 __attribute__((ext_vector_type(8)));

__device__ __forceinline__ unsigned int f2bf(float f) {
    union { float f; unsigned int u; } v; v.f = f;
    return (v.u + 0x7FFFu + ((v.u >> 16) & 1u)) >> 16;   // RNE f32->bf16 (bits)
}

__device__ __forceinline__ bf16x8 pack8(f32x4 a, f32x4 b) {
    union { bf16x8 v; __hip_bfloat162 h[4]; } u;
    u.h[0] = __float22bfloat162_rn(float2{a.x, a.y});
    u.h[1] = __float22bfloat162_rn(float2{a.z, a.w});
    u.h[2] = __float22bfloat162_rn(float2{b.x, b.y});
    u.h[3] = __float22bfloat162_rn(float2{b.z, b.w});
    return u.v;
}

// global -> LDS direct DMA, 16B per lane. dst is WAVE-UNIFORM base (HW adds
// lane*16); src is PER-LANE (pre-swizzled global address = swizzled LDS).
#define GLL16(SRC, DST)                                                        \
    __builtin_amdgcn_global_load_lds(                                          \
        (const __attribute__((address_space(1))) unsigned int*)(SRC),          \
        (__attribute__((address_space(3))) unsigned int*)(DST), 16, 0, 0)

// ---------------------------------------------------------------------------
// Kernel 0: W1 (16512x128 f32) -> W1T tiled bf16. Tile kt: [128 n][64 kl].
// ---------------------------------------------------------------------------
__global__ __launch_bounds__(256) void k_prep_w1t(const float* __restrict__ W1,
                                                  unsigned short* __restrict__ W1T) {
    __shared__ float tile[64][IN_DIM + 1];
    const int kt = blockIdx.x;               // 0..257
    const int t  = threadIdx.x;
    const float* src = W1 + (size_t)kt * 64 * IN_DIM;
#pragma unroll
    for (int p = 0; p < 8; ++p) {
        int c4 = p * 256 + t;
        int e = c4 * 4;
        int row = e >> 7, col = e & 127;
        f32x4 v = *reinterpret_cast<const f32x4*>(src + row * IN_DIM + col);
        tile[row][col+0] = v.x; tile[row][col+1] = v.y;
        tile[row][col+2] = v.z; tile[row][col+3] = v.w;
    }
    __syncthreads();
    unsigned short* dst = W1T + (size_t)kt * (IN_DIM * 64);
#pragma unroll
    for (int it = 0; it < 4; ++it) {
        int c = it * 256 + t;
        int n = c >> 3, kl0 = (c & 7) * 8;
        uint4 w;
        w.x = f2bf(tile[kl0+0][n]) | (f2bf(tile[kl0+1][n]) << 16);
        w.y = f2bf(tile[kl0+2][n]) | (f2bf(tile[kl0+3][n]) << 16);
        w.z = f2bf(tile[kl0+4][n]) | (f2bf(tile[kl0+5][n]) << 16);
        w.w = f2bf(tile[kl0+6][n]) | (f2bf(tile[kl0+7][n]) << 16);
        *reinterpret_cast<uint4*>(dst + c * 8) = w;
    }
}

// ---------------------------------------------------------------------------
// Kernel 1: split-K GEMM via global_load_lds (R16, +19.5µs win) + T4
// COUNTED VMCNT (m218 pattern): steady-state loop NEVER drains vmcnt to 0.
// Per iter: MFMA(cur) -> lgkmcnt(0)+barrier (retire buf cur) ->
// ISSUE(cur, tile i+2) -> s_waitcnt vmcnt(8) (tile i+1 landed; i+2's 8
// GLLs stay in flight) -> raw barrier -> swap. Loads get a full ~5Kcy
// iteration to land instead of the ~400cy MFMA phase (R16's residual
// stall: __syncthreads' vmcnt(0) drain right after issue).
// ---------------------------------------------------------------------------
__global__ __launch_bounds__(256) void k_gemm_M(const float* __restrict__ W2,
                                                const unsigned short* __restrict__ W1T,
                                                float* __restrict__ Mpart) {
    __shared__ __align__(16) unsigned char smem[65536];  // A f32: 2x16K @0; B bf16: 2x16K @32K
    float* trs = reinterpret_cast<float*>(smem);         // [32][132] epilogue alias

    const int t = threadIdx.x;
    const int lane = t & 63, wid = t >> 6;
    const int wm = wid >> 1, wn = wid & 1;    // wave grid 2m x 2n
    const int l15 = lane & 15, l4 = (lane >> 4) & 3;

    // bijective blockIdx -> (ks, mb); one XCD stays on one k-split (688KB
    // W1T slice L2-resident). 774 = 6*97 + 2*96.
    const int b = blockIdx.x;
    const int xcd = b & 7, slot = b >> 3;
    const int p = (xcd < 6) ? (xcd * 97 + slot) : (582 + (xcd - 6) * 96 + slot);
    const int ks = p / NMB, mb = p % NMB;

    const int m0 = mb * BM;
    const int g0 = ks * NT_PER;
    const int kt0 = (p * 7) % NT_PER;         // K-phase stagger (fp32 acc: safe)

    // ---- per-thread GLL source pointers (pre-swizzled; LDS stays linear) ----
    const int ca0 = wid * 4;
    const int rl0 = 4 * (ca0 + 0) + (lane >> 4);
    const int rl1 = 4 * (ca0 + 1) + (lane >> 4);
    const int rl2 = 4 * (ca0 + 2) + (lane >> 4);
    const int rl3 = 4 * (ca0 + 3) + (lane >> 4);
    const int acb = (lane & 15) * 16;         // LDS byte col within 256B row
    const float* aS0 = W2 + (size_t)(m0 + rl0) * K2 + (size_t)g0 * 64 + ((acb ^ ((rl0 & 7) << 4)) >> 2);
    const float* aS1 = W2 + (size_t)(m0 + rl1) * K2 + (size_t)g0 * 64 + ((acb ^ ((rl1 & 7) << 4)) >> 2);
    const float* aS2 = W2 + (size_t)(m0 + rl2) * K2 + (size_t)g0 * 64 + ((acb ^ ((rl2 & 7) << 4)) >> 2);
    const float* aS3 = W2 + (size_t)(m0 + rl3) * K2 + (size_t)g0 * 64 + ((acb ^ ((rl3 & 7) << 4)) >> 2);
    const int rb0 = 8 * (ca0 + 0) + (lane >> 3);
    const int rb1 = 8 * (ca0 + 1) + (lane >> 3);
    const int rb2 = 8 * (ca0 + 2) + (lane >> 3);
    const int rb3 = 8 * (ca0 + 3) + (lane >> 3);
    const int bcb = (lane & 7) * 16;
    const unsigned short* bS0 = W1T + (size_t)g0 * 8192 + rb0 * 64 + ((bcb ^ ((rb0 & 7) << 4)) >> 1);
    const unsigned short* bS1 = W1T + (size_t)g0 * 8192 + rb1 * 64 + ((bcb ^ ((rb1 & 7) << 4)) >> 1);
    const unsigned short* bS2 = W1T + (size_t)g0 * 8192 + rb2 * 64 + ((bcb ^ ((rb2 & 7) << 4)) >> 1);
    const unsigned short* bS3 = W1T + (size_t)g0 * 8192 + rb3 * 64 + ((bcb ^ ((rb3 & 7) << 4)) >> 1);
    const int aD = ca0 * 1024;                // wave-uniform LDS dest base

    f32x4 acc[2][4];
#pragma unroll
    for (int mf = 0; mf < 2; ++mf)
#pragma unroll
        for (int nf = 0; nf < 4; ++nf)
            acc[mf][nf] = (f32x4){0.f, 0.f, 0.f, 0.f};

#define ISSUE_AB(BUF, KT) {                                                    \
    unsigned char* _ab = smem + (BUF) * 16384;                                 \
    unsigned char* _bb = smem + 32768 + (BUF) * 16384;                         \
    const size_t _ao = (size_t)(KT) * 64;                                      \
    const size_t _bo = (size_t)(KT) * 8192;                                    \
    GLL16(aS0 + _ao, _ab + aD);                                                \
    GLL16(aS1 + _ao, _ab + aD + 1024);                                         \
    GLL16(aS2 + _ao, _ab + aD + 2048);                                         \
    GLL16(aS3 + _ao, _ab + aD + 3072);                                         \
    GLL16(bS0 + _bo, _bb + aD);                                                \
    GLL16(bS1 + _bo, _bb + aD + 1024);                                         \
    GLL16(bS2 + _bo, _bb + aD + 2048);                                         \
    GLL16(bS3 + _bo, _bb + aD + 3072);                                         \
}

#define MFMA_PHASE(BUF) {                                                      \
    const unsigned char* _Ash = smem + (BUF) * 16384;                          \
    const unsigned char* _Bsh = smem + 32768 + (BUF) * 16384;                  \
    _Pragma("unroll")                                                          \
    for (int kk = 0; kk < 2; ++kk) {                                           \
        const int _ar0 = wm * 32 + l15;                                        \
        const int _ar1 = wm * 32 + 16 + l15;                                   \
        const int _pb  = kk * 128 + l4 * 32;                                   \
        const int _s0  = (_ar0 & 7) << 4;                                      \
        const int _s1  = (_ar1 & 7) << 4;                                      \
        f32x4 _x0 = *reinterpret_cast<const f32x4*>(&_Ash[_ar0 * 256 + ((_pb)      ^ _s0)]); \
        f32x4 _x1 = *reinterpret_cast<const f32x4*>(&_Ash[_ar0 * 256 + ((_pb + 16) ^ _s0)]); \
        f32x4 _y0 = *reinterpret_cast<const f32x4*>(&_Ash[_ar1 * 256 + ((_pb)      ^ _s1)]); \
        f32x4 _y1 = *reinterpret_cast<const f32x4*>(&_Ash[_ar1 * 256 + ((_pb + 16) ^ _s1)]); \
        bf16x8 af0 = pack8(_x0, _x1);                                          \
        bf16x8 af1 = pack8(_y0, _y1);                                          \
        const int _fsw = (l15 & 7) << 4;                                       \
        const int _fc  = (kk * 64 + l4 * 16) ^ _fsw;                           \
        bf16x8 bf0 = *reinterpret_cast<const bf16x8*>(&_Bsh[(wn * 64 +  0 + l15) * 128 + _fc]); \
        bf16x8 bf1 = *reinterpret_cast<const bf16x8*>(&_Bsh[(wn * 64 + 16 + l15) * 128 + _fc]); \
        bf16x8 bf2 = *reinterpret_cast<const bf16x8*>(&_Bsh[(wn * 64 + 32 + l15) * 128 + _fc]); \
        bf16x8 bf3 = *reinterpret_cast<const bf16x8*>(&_Bsh[(wn * 64 + 48 + l15) * 128 + _fc]); \
        acc[0][0] = __builtin_amdgcn_mfma_f32_16x16x32_bf16(af0, bf0, acc[0][0], 0, 0, 0); \
        acc[0][1] = __builtin_amdgcn_mfma_f32_16x16x32_bf16(af0, bf1, acc[0][1], 0, 0, 0); \
        acc[0][2] = __builtin_amdgcn_mfma_f32_16x16x32_bf16(af0, bf2, acc[0][2], 0, 0, 0); \
        acc[0][3] = __builtin_amdgcn_mfma_f32_16x16x32_bf16(af0, bf3, acc[0][3], 0, 0, 0); \
        acc[1][0] = __builtin_amdgcn_mfma_f32_16x16x32_bf16(af1, bf0, acc[1][0], 0, 0, 0); \
        acc[1][1] = __builtin_amdgcn_mfma_f32_16x16x32_bf16(af1, bf1, acc[1][1], 0, 0, 0); \
        acc[1][2] = __builtin_amdgcn_mfma_f32_16x16x32_bf16(af1, bf2, acc[1][2], 0, 0, 0); \
        acc[1][3] = __builtin_amdgcn_mfma_f32_16x16x32_bf16(af1, bf3, acc[1][3], 0, 0, 0); \
    } }

#define LGKM_BAR() { asm volatile("s_waitcnt lgkmcnt(0)" ::: "memory");        \
                     __builtin_amdgcn_s_barrier();                             \
                     __builtin_amdgcn_sched_barrier(0); }
#define VMW(N)     { asm volatile("s_waitcnt vmcnt(" #N ")" ::: "memory");     \
                     __builtin_amdgcn_sched_barrier(0); }
#define BAR()      { __builtin_amdgcn_s_barrier();                             \
                     __builtin_amdgcn_sched_barrier(0); }

    // prologue: tile kt0 -> buf0, tile kt0+1 -> buf1 (in flight)
    int tcur = kt0;
    ISSUE_AB(0, tcur);
    { int tn = tcur + 1; if (tn >= NT_PER) tn = 0;
      ISSUE_AB(1, tn); tcur = tn; }
    VMW(8);                                   // tile kt0 landed
    BAR();

    int cur = 0;
#pragma unroll 1
    for (int i = 0; i < NT_PER; ++i) {
        MFMA_PHASE(cur);                      // tile i
        if (i + 1 < NT_PER) {
            LGKM_BAR();                       // retire buf cur (reads done)
            if (i + 2 < NT_PER) {
                int tn = tcur + 1; if (tn >= NT_PER) tn = 0;
                ISSUE_AB(cur, tn);            // tile i+2 -> buf cur
                tcur = tn;
                VMW(8);                       // tile i+1 landed; i+2 in flight
            } else {
                VMW(0);                       // last tile: full drain
            }
            BAR();                            // publish buf cur^1 to all waves
            cur ^= 1;
        }
    }

    // Epilogue: 2 rounds (wm groups); transpose via trs -> coalesced stores
    float* outp = Mpart + (size_t)ks * ((size_t)NFW * IN_DIM) + (size_t)m0 * IN_DIM;
#pragma unroll 1
    for (int w = 0; w < 2; ++w) {
        __syncthreads();
        if (wm == w) {
#pragma unroll
            for (int mf = 0; mf < 2; ++mf)
#pragma unroll
                for (int nf = 0; nf < 4; ++nf)
#pragma unroll
                    for (int r = 0; r < 4; ++r)
                        trs[(mf * 16 + l4 * 4 + r) * 132 + wn * 64 + nf * 16 + l15] = acc[mf][nf][r];
        }
        __syncthreads();
#pragma unroll
        for (int q = 0; q < 4; ++q) {
            int idx = q * 256 + t;            // 0..1023 (32 rows x 32 f32x4)
            int rr = idx >> 5, c4 = (idx & 31) << 2;
            f32x4 v = *reinterpret_cast<const f32x4*>(&trs[rr * 132 + c4]);
            *reinterpret_cast<f32x4*>(outp + (size_t)(w * 32 + rr) * IN_DIM + c4) = v;
        }
    }
#undef ISSUE_AB
#undef MFMA_PHASE
#undef LGKM_BAR
#undef VMW
#undef BAR
}

// ---------------------------------------------------------------------------
// Kernel 1b: reduce 6 partials -> M bf16. 264,192 f32x4 chunks.
// ---------------------------------------------------------------------------
__global__ __launch_bounds__(256) void k_reduce_M(const float* __restrict__ Mpart,
                                                  unsigned short* __restrict__ Mb) {
    const int idx = blockIdx.x * 256 + threadIdx.x;
    f32x4 s = (f32x4){0.f, 0.f, 0.f, 0.f};
#pragma unroll
    for (int ks = 0; ks < KSPLIT; ++ks) {
        f32x4 v = *reinterpret_cast<const f32x4*>(
            Mpart + (size_t)ks * ((size_t)NFW * IN_DIM) + (size_t)idx * 4);
        s.x += v.x; s.y += v.y; s.z += v.z; s.w += v.w;
    }
    uint2 o;
    o.x = f2bf(s.x) | (f2bf(s.y) << 16);
    o.y = f2bf(s.z) | (f2bf(s.w) << 16);
    *reinterpret_cast<uint2*>(Mb + (size_t)idx * 4) = o;
}

// ---------------------------------------------------------------------------
// Kernel 2 (fused U + chains): block = one 64-j slice. Phase 1: 4 waves
// compute U[256 i][64 j] into LDS; Phase 2: wave 0 runs the 64 sigmoid
// chains from LDS, streaming FW to HBM.
// ---------------------------------------------------------------------------
__global__ __launch_bounds__(256) void k_uchains(const float* __restrict__ xs,
                                                 const unsigned short* __restrict__ Mb,
                                                 const float* __restrict__ fw0,
                                                 float* __restrict__ FW) {
    __shared__ float Ulds[256][68];           // +4 pad
    const int t = threadIdx.x, lane = t & 63, wid = t >> 6;
    const int l15 = lane & 15, l4 = (lane >> 4) & 3;
    const int j0 = blockIdx.x * 64;

    bf16x8 bfr[4][4];                         // [kk][nf], static-indexed
#pragma unroll
    for (int kk = 0; kk < 4; ++kk)
#pragma unroll
        for (int nf = 0; nf < 4; ++nf)
            bfr[kk][nf] = *reinterpret_cast<const bf16x8*>(
                Mb + (size_t)(j0 + nf * 16 + l15) * IN_DIM + kk * 32 + l4 * 8);

#pragma unroll 1
    for (int ib = 0; ib < 4; ++ib) {
        const int i0 = wid * 64 + ib * 16;
        f32x4 acc[4];
#pragma unroll
        for (int nf = 0; nf < 4; ++nf) acc[nf] = (f32x4){0.f, 0.f, 0.f, 0.f};
#pragma unroll
        for (int kk = 0; kk < 4; ++kk) {
            const float* xp = xs + (size_t)(i0 + l15) * IN_DIM + kk * 32 + l4 * 8;
            f32x4 x0 = *reinterpret_cast<const f32x4*>(xp);
            f32x4 x1 = *reinterpret_cast<const f32x4*>(xp + 4);
            union { bf16x8 v; unsigned short s[8]; } af;
            af.s[0] = f2bf(x0.x); af.s[1] = f2bf(x0.y);
            af.s[2] = f2bf(x0.z); af.s[3] = f2bf(x0.w);
            af.s[4] = f2bf(x1.x); af.s[5] = f2bf(x1.y);
            af.s[6] = f2bf(x1.z); af.s[7] = f2bf(x1.w);
#pragma unroll
            for (int nf = 0; nf < 4; ++nf)
                acc[nf] = __builtin_amdgcn_mfma_f32_16x16x32_bf16(af.v, bfr[kk][nf], acc[nf], 0, 0, 0);
        }
#pragma unroll
        for (int nf = 0; nf < 4; ++nf)
#pragma unroll
            for (int r = 0; r < 4; ++r)
                Ulds[i0 + l4 * 4 + r][nf * 16 + l15] = acc[nf][r];
    }
    __syncthreads();

    if (wid == 0) {
        const int j = j0 + lane;
        float fw = fw0[j];
        float* fp = FW + j;
#pragma unroll 8
        for (int i = 0; i < BATCH; ++i) {
            float u = Ulds[i][lane];
            float z = 10.0f * (fw + u - 0.5f);
            fw = 1.0f / (1.0f + __expf(-z));
            fp[(size_t)i * NFW] = fw;
        }
    }
}

// ---------------------------------------------------------------------------
// Kernel 4: preds. Block per i: h = relu(fw1 @ xs_i), out[i] = fw2 . h.
// ---------------------------------------------------------------------------
__global__ __launch_bounds__(256) void k_preds(const float* __restrict__ FW,
                                               const float* __restrict__ xs,
                                               float* __restrict__ out) {
    __shared__ float xsh[IN_DIM];
    __shared__ float hsh[HID];
    const int i = blockIdx.x, t = threadIdx.x;
    if (t < 32) {
        f32x4 v = *reinterpret_cast<const f32x4*>(xs + (size_t)i * IN_DIM + t * 4);
        xsh[t*4+0] = v.x; xsh[t*4+1] = v.y; xsh[t*4+2] = v.z; xsh[t*4+3] = v.w;
    }
    __syncthreads();
    const int k = t >> 2, q = t & 3;
    const float* fr = FW + (size_t)i * NFW + k * IN_DIM + q * 32;
    float p = 0.f;
#pragma unroll
    for (int m = 0; m < 8; ++m) {
        f32x4 v = *reinterpret_cast<const f32x4*>(fr + m * 4);
        const int d = q * 32 + m * 4;
        p += v.x * xsh[d] + v.y * xsh[d+1] + v.z * xsh[d+2] + v.w * xsh[d+3];
    }
    p += __shfl_xor(p, 1);
    p += __shfl_xor(p, 2);
    if (q == 0) hsh[k] = fmaxf(p, 0.f);
    __syncthreads();
    if (t < 64) {
        float v = FW[(size_t)i * NFW + IN_DIM * HID + t] * hsh[t];
        v += __shfl_xor(v, 1);  v += __shfl_xor(v, 2);  v += __shfl_xor(v, 4);
        v += __shfl_xor(v, 8);  v += __shfl_xor(v, 16); v += __shfl_xor(v, 32);
        if (t == 0) out[i] = v;
    }
}

// ---------------------------------------------------------------------------
// Workspace layout (~40.2 MiB):
//   W1T  bf16 :  4,227,072 B @ 0
//   Mpart f32 : 25,362,432 B @  4,227,072   (6 x 8256 x 128)
//   Mb   bf16 :  2,113,536 B @ 29,589,504
//   FW   f32  :  8,454,144 B @ 31,703,040
// ---------------------------------------------------------------------------
extern "C" void kernel_launch(void* const* d_in, const int* in_sizes, int n_in,
                              void* d_out, int out_size, void* d_ws, size_t ws_size,
                              hipStream_t stream) {
    const float* x   = (const float*)d_in[0];   // (256,1,128)
    const float* W1  = (const float*)d_in[1];   // (16512,128)
    const float* W2  = (const float*)d_in[2];   // (8256,16512)
    const float* fw0 = (const float*)d_in[3];   // (8256,)
    float* out = (float*)d_out;                 // 256 f32

    char* ws = (char*)d_ws;
    unsigned short* W1T   = (unsigned short*)(ws);
    float*          Mpart = (float*)(ws + 4227072);
    unsigned short* Mb    = (unsigned short*)(ws + 29589504);
    float*          FW    = (float*)(ws + 31703040);

    hipLaunchKernelGGL(k_prep_w1t, dim3(258),    dim3(256), 0, stream, W1, W1T);
    hipLaunchKernelGGL(k_gemm_M,   dim3(GRID_M), dim3(256), 0, stream, W2, W1T, Mpart);
    hipLaunchKernelGGL(k_reduce_M, dim3(1032),   dim3(256), 0, stream, Mpart, Mb);
    hipLaunchKernelGGL(k_uchains,  dim3(129),    dim3(256), 0, stream, x, Mb, fw0, FW);
    hipLaunchKernelGGL(k_preds,    dim3(256),    dim3(256), 0, stream, FW, x, out);
}